// Round 5
// baseline (486.737 us; speedup 1.0000x reference)
//
#include <hip/hip_runtime.h>

// BigraphLightModel — R10: sorted-space SpMM + deeper build overlap.
//   R9 post-mortem: k_spmm8_final(g2) 48.5us, FETCH 123MB — degree-sort's
//   perm indirection randomized the epilogue row reads (x0/x1/x2) and out
//   write (~127MB of traffic scattered needlessly); g2 build tail (~40us)
//   fully exposed.
//   This round:
//    (a) g2 x-tables stored in SORTED space: evnorm remaps ev.x->sortpos[src]
//        (L2-resident table); spmm reads srr[vrow] linear, writes xn[vrow]
//        linear; final adds x0s/x1s/x2s linear, out[perm2[vrow]] scattered
//        (mandatory). Producers (g1 final, user cvt) compute sort position
//        inline (rr2/brk2 gather + per-block ghist rescan) and write
//        xb0_u[pos] directly — no staging, footprint unchanged (95.2MB).
//    (b) schedule: cnt2 concentrated F1-F4 (g1 build passes hidden in the
//        53us atomic floor); F5 [spmm1_g1|node2], F6 [spmm2_g1|fillE2],
//        F7 [final1|cvt2u_sorted|deg2|sortfin2], F8 [evnorm alone ~6us].
//   Per-XCD/atomic facts (R7/R8): scattered atomicAdd ~20-24 G/s invariant;
//   only hideable. SpMM inner loop (8-lane group, unroll-4, bf16) unchanged.

#define D       64
#define N_II    100000
#define N_UIU   200000
#define E_II    600000
#define E_UIU   1200000
#define N_USERS 100000
#define B       256
#define CR_K    8
#define FE_K    4

// ---------- bf16 helpers ----------
__device__ __forceinline__ unsigned short f2bf(float f) {
    unsigned u = __float_as_uint(f);
    u += 0x7fffu + ((u >> 16) & 1u);          // round-to-nearest-even
    return (unsigned short)(u >> 16);
}
__device__ __forceinline__ void bf8_fma(float acc[8], uint4 p, float v) {
    acc[0] += v * __uint_as_float(p.x << 16);
    acc[1] += v * __uint_as_float(p.x & 0xffff0000u);
    acc[2] += v * __uint_as_float(p.y << 16);
    acc[3] += v * __uint_as_float(p.y & 0xffff0000u);
    acc[4] += v * __uint_as_float(p.z << 16);
    acc[5] += v * __uint_as_float(p.z & 0xffff0000u);
    acc[6] += v * __uint_as_float(p.w << 16);
    acc[7] += v * __uint_as_float(p.w & 0xffff0000u);
}
__device__ __forceinline__ void bf8_add(float acc[8], uint4 p) {
    acc[0] += __uint_as_float(p.x << 16);
    acc[1] += __uint_as_float(p.x & 0xffff0000u);
    acc[2] += __uint_as_float(p.y << 16);
    acc[3] += __uint_as_float(p.y & 0xffff0000u);
    acc[4] += __uint_as_float(p.z << 16);
    acc[5] += __uint_as_float(p.z & 0xffff0000u);
    acc[6] += __uint_as_float(p.w << 16);
    acc[7] += __uint_as_float(p.w & 0xffff0000u);
}
__device__ __forceinline__ uint4 pack8(const float a[8]) {
    uint4 r;
    r.x = (unsigned)f2bf(a[0]) | ((unsigned)f2bf(a[1]) << 16);
    r.y = (unsigned)f2bf(a[2]) | ((unsigned)f2bf(a[3]) << 16);
    r.z = (unsigned)f2bf(a[4]) | ((unsigned)f2bf(a[5]) << 16);
    r.w = (unsigned)f2bf(a[6]) | ((unsigned)f2bf(a[7]) << 16);
    return r;
}

__device__ __forceinline__ int bin_of(int c) { return (c < 63) ? c : 63; }

// exclusive scan of ghist[64] into shared sboff[64] (wave 0); caller syncs.
__device__ __forceinline__ void scan_boff(const int* __restrict__ ghist, int* sboff) {
    int t = threadIdx.x;
    if (t < 64) {
        int v = ghist[t];
        int s = v;
        for (int o = 1; o < 64; o <<= 1) {
            int u = __shfl_up(s, o);
            if (t >= o) s += u;
        }
        sboff[t] = s - v;
    }
}

// ================= role device functions (bid = role-local block id) =================

// count+rank over edge range [e0,e1): K=8 batched, 1 atomic/edge.
__device__ __forceinline__ void rol_cnt(int bid, const int* __restrict__ dst,
                                        int* __restrict__ cnt, int* __restrict__ rank,
                                        int e0, int e1) {
    int base = e0 + bid * (B * CR_K) + threadIdx.x;
    int d[CR_K];
#pragma unroll
    for (int k = 0; k < CR_K; ++k) {
        int e = base + k * B;
        d[k] = (e < e1) ? dst[e] : 0;
    }
#pragma unroll
    for (int k = 0; k < CR_K; ++k) {
        int e = base + k * B;
        if (e < e1) rank[e] = atomicAdd(&cnt[d[k]], 1);
    }
}

// fp32 -> bf16 row conversion (thread = 8 dims), natural order
__device__ __forceinline__ void rol_cvt(int bid, const float4* __restrict__ x,
                                        uint4* __restrict__ xb, int n8) {
    int i = bid * B + threadIdx.x;
    if (i >= n8) return;
    float4 a = x[2 * i], b = x[2 * i + 1];
    float t[8] = {a.x, a.y, a.z, a.w, b.x, b.y, b.z, b.w};
    xb[i] = pack8(t);
}

// node pass: row-offset scan (order-free alloc) + 64-bin degree histogram + binrank
__device__ void rol_node(int bid, const int* __restrict__ cnt, int2* __restrict__ rr,
                         int* __restrict__ binrank, int* __restrict__ ghist,
                         int* __restrict__ gcur, int N) {
    __shared__ int sh[B];
    __shared__ int h[64], hb[64];
    __shared__ int sbase;
    int t = threadIdx.x;
    int i = bid * B + t;
    int c = (i < N) ? cnt[i] : 0;
    int b = bin_of(c);
    sh[t] = c;
    if (t < 64) h[t] = 0;
    __syncthreads();
    int rk = 0;
    if (i < N) rk = atomicAdd(&h[b], 1);
    for (int off = 1; off < B; off <<= 1) {   // inclusive scan
        int u = (t >= off) ? sh[t - off] : 0;
        __syncthreads();
        sh[t] += u;
        __syncthreads();
    }
    if (t == B - 1) sbase = atomicAdd(gcur, sh[B - 1]);
    if (t < 64) hb[t] = h[t] ? atomicAdd(&ghist[t], h[t]) : 0;
    __syncthreads();
    if (i < N) {
        int o = sbase + sh[t] - c;
        rr[i] = make_int2(o, o + c);
        binrank[i] = hb[b] + rk;
    }
}

// edge fill: coalesced reads, ONE scattered 8B store per edge (raw w payload)
__device__ __forceinline__ void rol_fillE(int bid, const int* __restrict__ src,
                                          const int* __restrict__ dst,
                                          const float* __restrict__ w,
                                          const int* __restrict__ rank,
                                          const int2* __restrict__ rr,
                                          int2* __restrict__ ev, int E) {
    int base = bid * (B * FE_K) + threadIdx.x;
    int d[FE_K], r[FE_K], s[FE_K];
    float ww[FE_K];
#pragma unroll
    for (int k = 0; k < FE_K; ++k) {
        int e = base + k * B;
        if (e < E) { d[k] = dst[e]; r[k] = rank[e]; s[k] = src[e]; ww[k] = w[e]; }
        else       { d[k] = 0; r[k] = 0; s[k] = 0; ww[k] = 0.f; }
    }
    int pos[FE_K];
#pragma unroll
    for (int k = 0; k < FE_K; ++k) pos[k] = rr[d[k]].x + r[k];
#pragma unroll
    for (int k = 0; k < FE_K; ++k) {
        int e = base + k * B;
        if (e < E) ev[pos[k]] = make_int2(s[k], __float_as_int(ww[k]));
    }
}

// weighted degree from CSR; dis = rsqrt(deg) or 0
__device__ __forceinline__ void rol_deg(int bid, const int2* __restrict__ rr,
                                        const int2* __restrict__ ev,
                                        float* __restrict__ dis, int N) {
    int i = bid * B + threadIdx.x;
    if (i >= N) return;
    int2 se = rr[i];
    float dg = 0.f;
    for (int j = se.x; j < se.y; ++j) dg += __int_as_float(ev[j].y);
    dis[i] = (dg > 0.f) ? rsqrtf(dg) : 0.f;
}

// g1: normalize ev in place + degree-sorted permutation scatter (orig-space scheme)
__device__ void rol_valsc(int bid, const int2* __restrict__ rr, const float* __restrict__ dis,
                          const int* __restrict__ binrank, const int* __restrict__ ghist,
                          int2* __restrict__ ev, int* __restrict__ perm,
                          int2* __restrict__ rrp, int N) {
    __shared__ int sboff[64];
    scan_boff(ghist, sboff);
    __syncthreads();
    int i = bid * B + threadIdx.x;
    if (i >= N) return;
    int2 se = rr[i];
    float di = dis[i];
    for (int j = se.x; j < se.y; ++j) {
        int2 p = ev[j];
        ev[j].y = __float_as_int(di * __int_as_float(p.y) * dis[p.x]);
    }
    int pos = sboff[bin_of(se.y - se.x)] + binrank[i];
    perm[pos] = i;
    rrp[pos]  = se;
}

// g2: sort finalize: sortpos[i] (linear), perm[pos]=i, srr[pos]=rr[i] (scatters)
__device__ void rol_sortfin(int bid, const int2* __restrict__ rr, const int* __restrict__ brk,
                            const int* __restrict__ ghist, int* __restrict__ sortpos,
                            int* __restrict__ perm, int2* __restrict__ srr, int N) {
    __shared__ int sboff[64];
    scan_boff(ghist, sboff);
    __syncthreads();
    int i = bid * B + threadIdx.x;
    if (i >= N) return;
    int2 se = rr[i];
    int pos = sboff[bin_of(se.y - se.x)] + brk[i];
    sortpos[i] = pos;
    perm[pos] = i;
    srr[pos]  = se;
}

// g2: normalize ev + remap ev.x into sorted space (sortpos gather, L2-resident)
__device__ __forceinline__ void rol_evnorm(int bid, const int2* __restrict__ rr,
                                           const float* __restrict__ dis,
                                           const int* __restrict__ sortpos,
                                           int2* __restrict__ ev, int N) {
    int i = bid * B + threadIdx.x;
    if (i >= N) return;
    int2 se = rr[i];
    float di = dis[i];
    for (int j = se.x; j < se.y; ++j) {
        int2 p = ev[j];
        ev[j] = make_int2(sortpos[p.x],
                          __float_as_int(di * __int_as_float(p.y) * dis[p.x]));
    }
}

// g2: fp32 user rows -> bf16 directly into SORTED x0 table (inline pos calc)
__device__ void rol_cvts(int bid, const float4* __restrict__ xu,
                         const int2* __restrict__ rr2, const int* __restrict__ brk2,
                         const int* __restrict__ ghist2, uint4* __restrict__ xb0s,
                         int Nrows) {
    __shared__ int sboff[64];
    scan_boff(ghist2, sboff);
    __syncthreads();
    int idx = bid * B + threadIdx.x;
    int row = idx >> 3;
    if (row >= Nrows) return;
    int g = idx & 7;
    int2 s2 = rr2[row];
    int pos = sboff[bin_of(s2.y - s2.x)] + brk2[row];
    float4 a = xu[(size_t)row * 16 + 2 * g], b = xu[(size_t)row * 16 + 2 * g + 1];
    float t[8] = {a.x, a.y, a.z, a.w, b.x, b.y, b.z, b.w};
    xb0s[(size_t)pos * 8 + g] = pack8(t);
}

// pull SpMM g1 (orig-space scheme, perm indirection)
__device__ void rol_spmm(int bid, const int2* __restrict__ rrp, const int* __restrict__ perm,
                         const int2* __restrict__ ev, const uint4* __restrict__ xb,
                         uint4* __restrict__ xn, int N) {
    int idx = bid * B + threadIdx.x;
    int vrow = idx >> 3;
    if (vrow >= N) return;
    int g = idx & 7;
    int2 se = rrp[vrow];
    int row = perm[vrow];
    float acc[8] = {0.f, 0.f, 0.f, 0.f, 0.f, 0.f, 0.f, 0.f};
    int j = se.x, e = se.y;
    for (; j + 3 < e; j += 4) {
        int2 p0 = ev[j], p1 = ev[j + 1], p2 = ev[j + 2], p3 = ev[j + 3];
        uint4 a0 = xb[(size_t)p0.x * 8 + g];
        uint4 a1 = xb[(size_t)p1.x * 8 + g];
        uint4 a2 = xb[(size_t)p2.x * 8 + g];
        uint4 a3 = xb[(size_t)p3.x * 8 + g];
        bf8_fma(acc, a0, __int_as_float(p0.y));
        bf8_fma(acc, a1, __int_as_float(p1.y));
        bf8_fma(acc, a2, __int_as_float(p2.y));
        bf8_fma(acc, a3, __int_as_float(p3.y));
    }
    for (; j < e; ++j) {
        int2 p0 = ev[j];
        uint4 a0 = xb[(size_t)p0.x * 8 + g];
        bf8_fma(acc, a0, __int_as_float(p0.y));
    }
    xn[(size_t)row * 8 + g] = pack8(acc);
}

// pull SpMM g2 (sorted space): linear srr read, linear xn write
__device__ void rol_spmm_s(int bid, const int2* __restrict__ srr, const int2* __restrict__ ev,
                           const uint4* __restrict__ xb, uint4* __restrict__ xn, int N) {
    int idx = bid * B + threadIdx.x;
    int vrow = idx >> 3;
    if (vrow >= N) return;
    int g = idx & 7;
    int2 se = srr[vrow];
    float acc[8] = {0.f, 0.f, 0.f, 0.f, 0.f, 0.f, 0.f, 0.f};
    int j = se.x, e = se.y;
    for (; j + 3 < e; j += 4) {
        int2 p0 = ev[j], p1 = ev[j + 1], p2 = ev[j + 2], p3 = ev[j + 3];
        uint4 a0 = xb[(size_t)p0.x * 8 + g];
        uint4 a1 = xb[(size_t)p1.x * 8 + g];
        uint4 a2 = xb[(size_t)p2.x * 8 + g];
        uint4 a3 = xb[(size_t)p3.x * 8 + g];
        bf8_fma(acc, a0, __int_as_float(p0.y));
        bf8_fma(acc, a1, __int_as_float(p1.y));
        bf8_fma(acc, a2, __int_as_float(p2.y));
        bf8_fma(acc, a3, __int_as_float(p3.y));
    }
    for (; j < e; ++j) {
        int2 p0 = ev[j];
        uint4 a0 = xb[(size_t)p0.x * 8 + g];
        bf8_fma(acc, a0, __int_as_float(p0.y));
    }
    xn[(size_t)vrow * 8 + g] = pack8(acc);
}

// g1 final: res = alpha*(x0+x1+x2+A*x2); writes bf16 item rows DIRECTLY into
// g2's sorted x0 table at inline-computed sort positions.
__device__ void rol_final1(int bid, const int2* __restrict__ rrp, const int* __restrict__ perm,
                           const int2* __restrict__ ev, const uint4* __restrict__ x2b,
                           const uint4* __restrict__ x1b, const uint4* __restrict__ x0b,
                           const int2* __restrict__ rr2, const int* __restrict__ brk2,
                           const int* __restrict__ ghist2, uint4* __restrict__ xb0s,
                           float alpha, int N) {
    __shared__ int sboff[64];
    scan_boff(ghist2, sboff);
    __syncthreads();
    int idx = bid * B + threadIdx.x;
    int vrow = idx >> 3;
    if (vrow >= N) return;
    int g = idx & 7;
    int2 se = rrp[vrow];
    int row = perm[vrow];
    float acc[8] = {0.f, 0.f, 0.f, 0.f, 0.f, 0.f, 0.f, 0.f};
    int j = se.x, e = se.y;
    for (; j + 3 < e; j += 4) {
        int2 p0 = ev[j], p1 = ev[j + 1], p2 = ev[j + 2], p3 = ev[j + 3];
        uint4 a0 = x2b[(size_t)p0.x * 8 + g];
        uint4 a1 = x2b[(size_t)p1.x * 8 + g];
        uint4 a2 = x2b[(size_t)p2.x * 8 + g];
        uint4 a3 = x2b[(size_t)p3.x * 8 + g];
        bf8_fma(acc, a0, __int_as_float(p0.y));
        bf8_fma(acc, a1, __int_as_float(p1.y));
        bf8_fma(acc, a2, __int_as_float(p2.y));
        bf8_fma(acc, a3, __int_as_float(p3.y));
    }
    for (; j < e; ++j) {
        int2 p0 = ev[j];
        uint4 a0 = x2b[(size_t)p0.x * 8 + g];
        bf8_fma(acc, a0, __int_as_float(p0.y));
    }
    bf8_add(acc, x1b[(size_t)row * 8 + g]);
    bf8_add(acc, x2b[(size_t)row * 8 + g]);
    bf8_add(acc, x0b[(size_t)row * 8 + g]);
    float r[8];
#pragma unroll
    for (int k = 0; k < 8; ++k) r[k] = alpha * acc[k];
    int oi = N_USERS + row;                       // orig id in g2 space
    int2 s2 = rr2[oi];
    int pos = sboff[bin_of(s2.y - s2.x)] + brk2[oi];
    xb0s[(size_t)pos * 8 + g] = pack8(r);
}

// g2 final (sorted space): linear x0s/x1s/x2s adds; out[perm[vrow]] fp32 scatter
__device__ void rol_final_s(int bid, const int2* __restrict__ srr, const int* __restrict__ perm,
                            const int2* __restrict__ ev, const uint4* __restrict__ x2s,
                            const uint4* __restrict__ x1s, const uint4* __restrict__ x0s,
                            float4* __restrict__ out, float alpha, int N) {
    int idx = bid * B + threadIdx.x;
    int vrow = idx >> 3;
    if (vrow >= N) return;
    int g = idx & 7;
    int2 se = srr[vrow];
    float acc[8] = {0.f, 0.f, 0.f, 0.f, 0.f, 0.f, 0.f, 0.f};
    int j = se.x, e = se.y;
    for (; j + 3 < e; j += 4) {
        int2 p0 = ev[j], p1 = ev[j + 1], p2 = ev[j + 2], p3 = ev[j + 3];
        uint4 a0 = x2s[(size_t)p0.x * 8 + g];
        uint4 a1 = x2s[(size_t)p1.x * 8 + g];
        uint4 a2 = x2s[(size_t)p2.x * 8 + g];
        uint4 a3 = x2s[(size_t)p3.x * 8 + g];
        bf8_fma(acc, a0, __int_as_float(p0.y));
        bf8_fma(acc, a1, __int_as_float(p1.y));
        bf8_fma(acc, a2, __int_as_float(p2.y));
        bf8_fma(acc, a3, __int_as_float(p3.y));
    }
    for (; j < e; ++j) {
        int2 p0 = ev[j];
        uint4 a0 = x2s[(size_t)p0.x * 8 + g];
        bf8_fma(acc, a0, __int_as_float(p0.y));
    }
    bf8_add(acc, x1s[(size_t)vrow * 8 + g]);
    bf8_add(acc, x2s[(size_t)vrow * 8 + g]);
    bf8_add(acc, x0s[(size_t)vrow * 8 + g]);
    float r[8];
#pragma unroll
    for (int k = 0; k < 8; ++k) r[k] = alpha * acc[k];
    int orig = perm[vrow];
    out[(size_t)orig * 16 + 2 * g]     = make_float4(r[0], r[1], r[2], r[3]);
    out[(size_t)orig * 16 + 2 * g + 1] = make_float4(r[4], r[5], r[6], r[7]);
}

// ================= fused dispatch kernels (blockIdx range -> role) =================

__global__ void f_cnt_cvt(int nbA, const int* dstA, int* cntA, int* rankA, int eA,
                          const float4* xB, uint4* xbB, int n8B) {
    int b = (int)blockIdx.x;
    if (b < nbA) rol_cnt(b, dstA, cntA, rankA, 0, eA);
    else         rol_cvt(b - nbA, xB, xbB, n8B);
}

__global__ void f_node_cnt(int nbA, const int* cntN, int2* rr, int* brk, int* ghist,
                           int* gcur, int N,
                           const int* dstS, int* cntS, int* rankS, int e0, int e1) {
    int b = (int)blockIdx.x;
    if (b < nbA) rol_node(b, cntN, rr, brk, ghist, gcur, N);
    else         rol_cnt(b - nbA, dstS, cntS, rankS, e0, e1);
}

__global__ void f_fillE_cnt(int nbA, const int* src, const int* dst, const float* w,
                            const int* rank, const int2* rr, int2* ev, int E,
                            const int* dstS, int* cntS, int* rankS, int e0, int e1) {
    int b = (int)blockIdx.x;
    if (b < nbA) rol_fillE(b, src, dst, w, rank, rr, ev, E);
    else         rol_cnt(b - nbA, dstS, cntS, rankS, e0, e1);
}

__global__ void f_deg_cnt(int nbA, const int2* rr, const int2* ev, float* dis, int N,
                          const int* dstS, int* cntS, int* rankS, int e0, int e1) {
    int b = (int)blockIdx.x;
    if (b < nbA) rol_deg(b, rr, ev, dis, N);
    else         rol_cnt(b - nbA, dstS, cntS, rankS, e0, e1);
}

__global__ void f_valsc_cnt(int nbA, const int2* rr, const float* dis, const int* brk,
                            const int* ghist, int2* ev, int* perm, int2* rrp, int N,
                            const int* dstS, int* cntS, int* rankS, int e0, int e1) {
    int b = (int)blockIdx.x;
    if (b < nbA) rol_valsc(b, rr, dis, brk, ghist, ev, perm, rrp, N);
    else         rol_cnt(b - nbA, dstS, cntS, rankS, e0, e1);
}

__global__ void f_spmm_node(int nbA, const int2* rrp, const int* perm, const int2* ev,
                            const uint4* xb, uint4* xn, int NA,
                            const int* cntN, int2* rrB, int* brkB, int* ghistB,
                            int* gcurB, int NB) {
    int b = (int)blockIdx.x;
    if (b < nbA) rol_spmm(b, rrp, perm, ev, xb, xn, NA);
    else         rol_node(b - nbA, cntN, rrB, brkB, ghistB, gcurB, NB);
}

__global__ void f_spmm_fill(int nbA, const int2* rrp, const int* perm, const int2* ev,
                            const uint4* xb, uint4* xn, int NA,
                            const int* srcB, const int* dstB, const float* wB,
                            const int* rankB, const int2* rrB, int2* evB, int EB) {
    int b = (int)blockIdx.x;
    if (b < nbA) rol_spmm(b, rrp, perm, ev, xb, xn, NA);
    else         rol_fillE(b - nbA, srcB, dstB, wB, rankB, rrB, evB, EB);
}

// F7: [final1 | cvt2u_sorted | deg2 | sortfin2]
__global__ void f_final_mix(int nbA, const int2* rrp1, const int* perm1, const int2* ev1,
                            const uint4* x2b, const uint4* x1b, const uint4* x0b,
                            float alpha, int N1,
                            int nbB, const float4* xu,
                            int nbC, const int2* rr2, const int2* ev2, float* dis2, int N2,
                            const int* brk2, const int* ghist2, uint4* xb0s,
                            int* sortpos2, int* perm2, int2* srr2) {
    int b = (int)blockIdx.x;
    if (b < nbA) { rol_final1(b, rrp1, perm1, ev1, x2b, x1b, x0b,
                              rr2, brk2, ghist2, xb0s, alpha, N1); return; }
    b -= nbA;
    if (b < nbB) { rol_cvts(b, xu, rr2, brk2, ghist2, xb0s, N_USERS); return; }
    b -= nbB;
    if (b < nbC) { rol_deg(b, rr2, ev2, dis2, N2); return; }
    rol_sortfin(b - nbC, rr2, brk2, ghist2, sortpos2, perm2, srr2, N2);
}

__global__ void k_evnorm(const int2* rr, const float* dis, const int* sortpos,
                         int2* ev, int N) {
    rol_evnorm((int)blockIdx.x, rr, dis, sortpos, ev, N);
}
__global__ void k_spmm_s(const int2* srr, const int2* ev, const uint4* xb,
                         uint4* xn, int N) {
    rol_spmm_s((int)blockIdx.x, srr, ev, xb, xn, N);
}
__global__ void k_final_s(const int2* srr, const int* perm, const int2* ev,
                          const uint4* x2s, const uint4* x1s, const uint4* x0s,
                          float4* out, float alpha, int N) {
    rol_final_s((int)blockIdx.x, srr, perm, ev, x2s, x1s, x0s, out, alpha, N);
}

// ================= host-side orchestration =================

static inline int nbx(long long work, int per) { return (int)((work + per - 1) / per); }

extern "C" void kernel_launch(void* const* d_in, const int* in_sizes, int n_in,
                              void* d_out, int out_size, void* d_ws, size_t ws_size,
                              hipStream_t stream) {
    const float* emb_ii  = (const float*)d_in[0];
    const float* emb_uiu = (const float*)d_in[1];
    const float* w_ii    = (const float*)d_in[2];
    const float* w_uiu   = (const float*)d_in[3];
    const int*   src_ii  = (const int*)d_in[4];
    const int*   dst_ii  = src_ii + E_II;
    const int*   src_uiu = (const int*)d_in[5];
    const int*   dst_uiu = src_uiu + E_UIU;
    float*       out     = (float*)d_out;

    // ---- workspace (95.2 MB, same as R9) ----
    // xb0_u: g2 SORTED x0 (written F7, read F9/F11)
    // x1_u : [g1_x0 | g1_x1] until F7, then g2 z1 (sorted, F9+)
    // x2_u : [g1_x2 (1st half) | g1 build block (2nd half)] until F7, then g2 z2
    // tail : g2 build block (18.4MB): ev2|rank2(perm2,srr2 alias)|rr2|cnt2(sortpos2
    //        alias)+gt2|brk2|dis2
    uint4* xb0_u = (uint4*)d_ws;
    uint4* x1_u  = xb0_u + (size_t)N_UIU * 8;
    uint4* x2_u  = x1_u + (size_t)N_UIU * 8;

    // g1 build block in x2_u second half (dead after F7; z2 written F10)
    int2*  ev1   = (int2*)(x2_u + (size_t)N_II * 8);
    int*   rank1 = (int*)(ev1 + E_II);
    int2*  rr1   = (int2*)(rank1 + E_II);
    int*   cnt1  = (int*)(rr1 + N_II);
    int*   gt1   = cnt1 + N_II;                 // gcur | ghist[64]
    float* dis1  = (float*)(gt1 + 65);
    int*   brk1  = (int*)(dis1 + N_II);
    int*   perm1 = rank1;                       // alias post-fillE1
    int2*  rrp1  = (int2*)(rank1 + N_II);

    // g2 build block (tail)
    int2*  ev2   = (int2*)(x2_u + (size_t)N_UIU * 8);
    int*   rank2 = (int*)(ev2 + E_UIU);
    int*   perm2 = rank2;                       // alias: written F7 (rank2 dead after F6)
    int2*  srr2  = (int2*)(rank2 + N_UIU);      // alias, same region
    int2*  rr2   = (int2*)(rank2 + E_UIU);
    int*   cnt2  = (int*)(rr2 + N_UIU);
    int*   sortpos2 = cnt2;                     // alias: written F7 (cnt2 dead after F5)
    int*   gt2   = cnt2 + N_UIU;                // gcur | ghist[64]
    int*   brk2  = gt2 + 65;
    float* dis2  = (float*)(brk2 + N_UIU);

    uint4* g1_x0 = x1_u;                         // 12.8MB
    uint4* g1_x1 = x1_u + (size_t)N_II * 8;      // 12.8MB
    uint4* g1_x2 = x2_u;                         // 12.8MB (x2_u 1st half)

    const float alpha = 0.25f;    // 1/(L+1), L=3 both graphs

    hipMemsetAsync(cnt1, 0, ((size_t)N_II + 65) * sizeof(int), stream);
    hipMemsetAsync(cnt2, 0, ((size_t)N_UIU + 65) * sizeof(int), stream);

    // cnt2 slice boundaries: 4 x 300K edges across F1-F4 (the 53us atomic floor;
    // g1's node/fillE/deg/valsc hidden inside)
    const int s[5] = {0, 300000, 600000, 900000, E_UIU};

    const int nbCnt1 = nbx(E_II, B * CR_K);
    const int nbCvt1 = nbx((long long)N_II * 8, B);
    const int nbN1   = nbx(N_II, B);
    const int nbF1   = nbx(E_II, B * FE_K);
    const int nbS1   = nbx((long long)N_II * 8, B);
    const int nbN2   = nbx(N_UIU, B);
    const int nbF2   = nbx(E_UIU, B * FE_K);
    const int nbS2   = nbx((long long)N_UIU * 8, B);
    const int nbCvt2 = nbx((long long)N_USERS * 8, B);

    // F0: g1 count | g1 x0 bf16 conversion
    f_cnt_cvt<<<nbCnt1 + nbCvt1, B, 0, stream>>>(
        nbCnt1, dst_ii, cnt1, rank1, E_II,
        (const float4*)emb_ii, g1_x0, N_II * 8);

    // F1: g1 node | cnt2 slice 0
    f_node_cnt<<<nbN1 + nbx(s[1] - s[0], B * CR_K), B, 0, stream>>>(
        nbN1, cnt1, rr1, brk1, gt1 + 1, gt1, N_II,
        dst_uiu, cnt2, rank2, s[0], s[1]);

    // F2: g1 fillE | cnt2 slice 1
    f_fillE_cnt<<<nbF1 + nbx(s[2] - s[1], B * CR_K), B, 0, stream>>>(
        nbF1, src_ii, dst_ii, w_ii, rank1, rr1, ev1, E_II,
        dst_uiu, cnt2, rank2, s[1], s[2]);

    // F3: g1 deg | cnt2 slice 2
    f_deg_cnt<<<nbN1 + nbx(s[3] - s[2], B * CR_K), B, 0, stream>>>(
        nbN1, rr1, ev1, dis1, N_II,
        dst_uiu, cnt2, rank2, s[2], s[3]);

    // F4: g1 val+scatter | cnt2 slice 3 (cnt2 complete)
    f_valsc_cnt<<<nbN1 + nbx(s[4] - s[3], B * CR_K), B, 0, stream>>>(
        nbN1, rr1, dis1, brk1, gt1 + 1, ev1, perm1, rrp1, N_II,
        dst_uiu, cnt2, rank2, s[3], s[4]);

    // F5: g1 spmm layer1 | g2 node
    f_spmm_node<<<nbS1 + nbN2, B, 0, stream>>>(
        nbS1, rrp1, perm1, ev1, g1_x0, g1_x1, N_II,
        cnt2, rr2, brk2, gt2 + 1, gt2, N_UIU);

    // F6: g1 spmm layer2 | g2 fillE
    f_spmm_fill<<<nbS1 + nbF2, B, 0, stream>>>(
        nbS1, rrp1, perm1, ev1, g1_x1, g1_x2, N_II,
        src_uiu, dst_uiu, w_uiu, rank2, rr2, ev2, E_UIU);

    // F7: g1 final (bf16 item rows -> sorted g2 x0) | cvt2u sorted | g2 deg | g2 sortfin
    f_final_mix<<<nbS1 + nbCvt2 + nbN2 + nbN2, B, 0, stream>>>(
        nbS1, rrp1, perm1, ev1, g1_x2, g1_x1, g1_x0, alpha, N_II,
        nbCvt2, (const float4*)emb_uiu,
        nbN2, rr2, ev2, dis2, N_UIU,
        brk2, gt2 + 1, xb0_u, sortpos2, perm2, srr2);

    // F8: g2 evnorm (normalize + remap ev.x -> sorted)
    k_evnorm<<<nbN2, B, 0, stream>>>(rr2, dis2, sortpos2, ev2, N_UIU);

    // F9-F11: g2 spmm chain in sorted space
    k_spmm_s<<<nbS2, B, 0, stream>>>(srr2, ev2, xb0_u, x1_u, N_UIU);
    k_spmm_s<<<nbS2, B, 0, stream>>>(srr2, ev2, x1_u, x2_u, N_UIU);
    k_final_s<<<nbS2, B, 0, stream>>>(srr2, perm2, ev2, x2_u, x1_u, xb0_u,
                                      (float4*)out, alpha, N_UIU);
}

// Round 7
// 478.857 us; speedup vs baseline: 1.0165x; 1.0165x over previous
//
#include <hip/hip_runtime.h>

// BigraphLightModel — R12 (= R11 resubmit; prior bench died to container
//   infra flake, no kernel signal).
//   R10 post-mortem: f_spmm_fill [spmm2_g1|fillE2] = 60us @ 2.1TB/s — worse
//   than serial (16+32). Rule learned: atomic-cnt is a benign co-tenant
//   (low BW/footprint; R9 f_spmm_cnt fine), but scatter-store (fillE)
//   paired with gather (spmm) thrashes per-XCD L2 => both slow.
//   This round (roles + aliasing IDENTICAL to R10; schedule only):
//     F0 [cnt1|cvt1]; F1-F5 [node1/fillE1/deg1/valsc1/spmm1_g1 | cnt2 x5];
//     F6 [spmm2_g1|node2]; F7 fillE2 ALONE; F8 [final1|cvt2s|deg2|sortfin2];
//     F9 evnorm; F10-F12 sorted-space g2 spmm chain.
//   Alias legality: perm2/srr2 <- rank2 (dead after F7), sortpos2 <- cnt2
//   (dead after F6) — unchanged from R10.
//   Facts bank: scattered atomicAdd ~20-24G/s invariant (R7/R8); sorted-space
//   SpMM linearizes epilogue+writes (R10); gather fetch ~76% L3-absorbed.

#define D       64
#define N_II    100000
#define N_UIU   200000
#define E_II    600000
#define E_UIU   1200000
#define N_USERS 100000
#define B       256
#define CR_K    8
#define FE_K    4

// ---------- bf16 helpers ----------
__device__ __forceinline__ unsigned short f2bf(float f) {
    unsigned u = __float_as_uint(f);
    u += 0x7fffu + ((u >> 16) & 1u);          // round-to-nearest-even
    return (unsigned short)(u >> 16);
}
__device__ __forceinline__ void bf8_fma(float acc[8], uint4 p, float v) {
    acc[0] += v * __uint_as_float(p.x << 16);
    acc[1] += v * __uint_as_float(p.x & 0xffff0000u);
    acc[2] += v * __uint_as_float(p.y << 16);
    acc[3] += v * __uint_as_float(p.y & 0xffff0000u);
    acc[4] += v * __uint_as_float(p.z << 16);
    acc[5] += v * __uint_as_float(p.z & 0xffff0000u);
    acc[6] += v * __uint_as_float(p.w << 16);
    acc[7] += v * __uint_as_float(p.w & 0xffff0000u);
}
__device__ __forceinline__ void bf8_add(float acc[8], uint4 p) {
    acc[0] += __uint_as_float(p.x << 16);
    acc[1] += __uint_as_float(p.x & 0xffff0000u);
    acc[2] += __uint_as_float(p.y << 16);
    acc[3] += __uint_as_float(p.y & 0xffff0000u);
    acc[4] += __uint_as_float(p.z << 16);
    acc[5] += __uint_as_float(p.z & 0xffff0000u);
    acc[6] += __uint_as_float(p.w << 16);
    acc[7] += __uint_as_float(p.w & 0xffff0000u);
}
__device__ __forceinline__ uint4 pack8(const float a[8]) {
    uint4 r;
    r.x = (unsigned)f2bf(a[0]) | ((unsigned)f2bf(a[1]) << 16);
    r.y = (unsigned)f2bf(a[2]) | ((unsigned)f2bf(a[3]) << 16);
    r.z = (unsigned)f2bf(a[4]) | ((unsigned)f2bf(a[5]) << 16);
    r.w = (unsigned)f2bf(a[6]) | ((unsigned)f2bf(a[7]) << 16);
    return r;
}

__device__ __forceinline__ int bin_of(int c) { return (c < 63) ? c : 63; }

// exclusive scan of ghist[64] into shared sboff[64] (wave 0); caller syncs.
__device__ __forceinline__ void scan_boff(const int* __restrict__ ghist, int* sboff) {
    int t = threadIdx.x;
    if (t < 64) {
        int v = ghist[t];
        int s = v;
        for (int o = 1; o < 64; o <<= 1) {
            int u = __shfl_up(s, o);
            if (t >= o) s += u;
        }
        sboff[t] = s - v;
    }
}

// ================= role device functions (bid = role-local block id) =================

// count+rank over edge range [e0,e1): K=8 batched, 1 atomic/edge.
__device__ __forceinline__ void rol_cnt(int bid, const int* __restrict__ dst,
                                        int* __restrict__ cnt, int* __restrict__ rank,
                                        int e0, int e1) {
    int base = e0 + bid * (B * CR_K) + threadIdx.x;
    int d[CR_K];
#pragma unroll
    for (int k = 0; k < CR_K; ++k) {
        int e = base + k * B;
        d[k] = (e < e1) ? dst[e] : 0;
    }
#pragma unroll
    for (int k = 0; k < CR_K; ++k) {
        int e = base + k * B;
        if (e < e1) rank[e] = atomicAdd(&cnt[d[k]], 1);
    }
}

// fp32 -> bf16 row conversion (thread = 8 dims), natural order
__device__ __forceinline__ void rol_cvt(int bid, const float4* __restrict__ x,
                                        uint4* __restrict__ xb, int n8) {
    int i = bid * B + threadIdx.x;
    if (i >= n8) return;
    float4 a = x[2 * i], b = x[2 * i + 1];
    float t[8] = {a.x, a.y, a.z, a.w, b.x, b.y, b.z, b.w};
    xb[i] = pack8(t);
}

// node pass: row-offset scan (order-free alloc) + 64-bin degree histogram + binrank
__device__ void rol_node(int bid, const int* __restrict__ cnt, int2* __restrict__ rr,
                         int* __restrict__ binrank, int* __restrict__ ghist,
                         int* __restrict__ gcur, int N) {
    __shared__ int sh[B];
    __shared__ int h[64], hb[64];
    __shared__ int sbase;
    int t = threadIdx.x;
    int i = bid * B + t;
    int c = (i < N) ? cnt[i] : 0;
    int b = bin_of(c);
    sh[t] = c;
    if (t < 64) h[t] = 0;
    __syncthreads();
    int rk = 0;
    if (i < N) rk = atomicAdd(&h[b], 1);
    for (int off = 1; off < B; off <<= 1) {   // inclusive scan
        int u = (t >= off) ? sh[t - off] : 0;
        __syncthreads();
        sh[t] += u;
        __syncthreads();
    }
    if (t == B - 1) sbase = atomicAdd(gcur, sh[B - 1]);
    if (t < 64) hb[t] = h[t] ? atomicAdd(&ghist[t], h[t]) : 0;
    __syncthreads();
    if (i < N) {
        int o = sbase + sh[t] - c;
        rr[i] = make_int2(o, o + c);
        binrank[i] = hb[b] + rk;
    }
}

// edge fill: coalesced reads, ONE scattered 8B store per edge (raw w payload)
__device__ __forceinline__ void rol_fillE(int bid, const int* __restrict__ src,
                                          const int* __restrict__ dst,
                                          const float* __restrict__ w,
                                          const int* __restrict__ rank,
                                          const int2* __restrict__ rr,
                                          int2* __restrict__ ev, int E) {
    int base = bid * (B * FE_K) + threadIdx.x;
    int d[FE_K], r[FE_K], s[FE_K];
    float ww[FE_K];
#pragma unroll
    for (int k = 0; k < FE_K; ++k) {
        int e = base + k * B;
        if (e < E) { d[k] = dst[e]; r[k] = rank[e]; s[k] = src[e]; ww[k] = w[e]; }
        else       { d[k] = 0; r[k] = 0; s[k] = 0; ww[k] = 0.f; }
    }
    int pos[FE_K];
#pragma unroll
    for (int k = 0; k < FE_K; ++k) pos[k] = rr[d[k]].x + r[k];
#pragma unroll
    for (int k = 0; k < FE_K; ++k) {
        int e = base + k * B;
        if (e < E) ev[pos[k]] = make_int2(s[k], __float_as_int(ww[k]));
    }
}

// weighted degree from CSR; dis = rsqrt(deg) or 0
__device__ __forceinline__ void rol_deg(int bid, const int2* __restrict__ rr,
                                        const int2* __restrict__ ev,
                                        float* __restrict__ dis, int N) {
    int i = bid * B + threadIdx.x;
    if (i >= N) return;
    int2 se = rr[i];
    float dg = 0.f;
    for (int j = se.x; j < se.y; ++j) dg += __int_as_float(ev[j].y);
    dis[i] = (dg > 0.f) ? rsqrtf(dg) : 0.f;
}

// g1: normalize ev in place + degree-sorted permutation scatter (orig-space scheme)
__device__ void rol_valsc(int bid, const int2* __restrict__ rr, const float* __restrict__ dis,
                          const int* __restrict__ binrank, const int* __restrict__ ghist,
                          int2* __restrict__ ev, int* __restrict__ perm,
                          int2* __restrict__ rrp, int N) {
    __shared__ int sboff[64];
    scan_boff(ghist, sboff);
    __syncthreads();
    int i = bid * B + threadIdx.x;
    if (i >= N) return;
    int2 se = rr[i];
    float di = dis[i];
    for (int j = se.x; j < se.y; ++j) {
        int2 p = ev[j];
        ev[j].y = __float_as_int(di * __int_as_float(p.y) * dis[p.x]);
    }
    int pos = sboff[bin_of(se.y - se.x)] + binrank[i];
    perm[pos] = i;
    rrp[pos]  = se;
}

// g2: sort finalize: sortpos[i] (linear), perm[pos]=i, srr[pos]=rr[i] (scatters)
__device__ void rol_sortfin(int bid, const int2* __restrict__ rr, const int* __restrict__ brk,
                            const int* __restrict__ ghist, int* __restrict__ sortpos,
                            int* __restrict__ perm, int2* __restrict__ srr, int N) {
    __shared__ int sboff[64];
    scan_boff(ghist, sboff);
    __syncthreads();
    int i = bid * B + threadIdx.x;
    if (i >= N) return;
    int2 se = rr[i];
    int pos = sboff[bin_of(se.y - se.x)] + brk[i];
    sortpos[i] = pos;
    perm[pos] = i;
    srr[pos]  = se;
}

// g2: normalize ev + remap ev.x into sorted space (sortpos gather, L2-resident)
__device__ __forceinline__ void rol_evnorm(int bid, const int2* __restrict__ rr,
                                           const float* __restrict__ dis,
                                           const int* __restrict__ sortpos,
                                           int2* __restrict__ ev, int N) {
    int i = bid * B + threadIdx.x;
    if (i >= N) return;
    int2 se = rr[i];
    float di = dis[i];
    for (int j = se.x; j < se.y; ++j) {
        int2 p = ev[j];
        ev[j] = make_int2(sortpos[p.x],
                          __float_as_int(di * __int_as_float(p.y) * dis[p.x]));
    }
}

// g2: fp32 user rows -> bf16 directly into SORTED x0 table (inline pos calc)
__device__ void rol_cvts(int bid, const float4* __restrict__ xu,
                         const int2* __restrict__ rr2, const int* __restrict__ brk2,
                         const int* __restrict__ ghist2, uint4* __restrict__ xb0s,
                         int Nrows) {
    __shared__ int sboff[64];
    scan_boff(ghist2, sboff);
    __syncthreads();
    int idx = bid * B + threadIdx.x;
    int row = idx >> 3;
    if (row >= Nrows) return;
    int g = idx & 7;
    int2 s2 = rr2[row];
    int pos = sboff[bin_of(s2.y - s2.x)] + brk2[row];
    float4 a = xu[(size_t)row * 16 + 2 * g], b = xu[(size_t)row * 16 + 2 * g + 1];
    float t[8] = {a.x, a.y, a.z, a.w, b.x, b.y, b.z, b.w};
    xb0s[(size_t)pos * 8 + g] = pack8(t);
}

// pull SpMM g1 (orig-space scheme, perm indirection)
__device__ void rol_spmm(int bid, const int2* __restrict__ rrp, const int* __restrict__ perm,
                         const int2* __restrict__ ev, const uint4* __restrict__ xb,
                         uint4* __restrict__ xn, int N) {
    int idx = bid * B + threadIdx.x;
    int vrow = idx >> 3;
    if (vrow >= N) return;
    int g = idx & 7;
    int2 se = rrp[vrow];
    int row = perm[vrow];
    float acc[8] = {0.f, 0.f, 0.f, 0.f, 0.f, 0.f, 0.f, 0.f};
    int j = se.x, e = se.y;
    for (; j + 3 < e; j += 4) {
        int2 p0 = ev[j], p1 = ev[j + 1], p2 = ev[j + 2], p3 = ev[j + 3];
        uint4 a0 = xb[(size_t)p0.x * 8 + g];
        uint4 a1 = xb[(size_t)p1.x * 8 + g];
        uint4 a2 = xb[(size_t)p2.x * 8 + g];
        uint4 a3 = xb[(size_t)p3.x * 8 + g];
        bf8_fma(acc, a0, __int_as_float(p0.y));
        bf8_fma(acc, a1, __int_as_float(p1.y));
        bf8_fma(acc, a2, __int_as_float(p2.y));
        bf8_fma(acc, a3, __int_as_float(p3.y));
    }
    for (; j < e; ++j) {
        int2 p0 = ev[j];
        uint4 a0 = xb[(size_t)p0.x * 8 + g];
        bf8_fma(acc, a0, __int_as_float(p0.y));
    }
    xn[(size_t)row * 8 + g] = pack8(acc);
}

// pull SpMM g2 (sorted space): linear srr read, linear xn write
__device__ void rol_spmm_s(int bid, const int2* __restrict__ srr, const int2* __restrict__ ev,
                           const uint4* __restrict__ xb, uint4* __restrict__ xn, int N) {
    int idx = bid * B + threadIdx.x;
    int vrow = idx >> 3;
    if (vrow >= N) return;
    int g = idx & 7;
    int2 se = srr[vrow];
    float acc[8] = {0.f, 0.f, 0.f, 0.f, 0.f, 0.f, 0.f, 0.f};
    int j = se.x, e = se.y;
    for (; j + 3 < e; j += 4) {
        int2 p0 = ev[j], p1 = ev[j + 1], p2 = ev[j + 2], p3 = ev[j + 3];
        uint4 a0 = xb[(size_t)p0.x * 8 + g];
        uint4 a1 = xb[(size_t)p1.x * 8 + g];
        uint4 a2 = xb[(size_t)p2.x * 8 + g];
        uint4 a3 = xb[(size_t)p3.x * 8 + g];
        bf8_fma(acc, a0, __int_as_float(p0.y));
        bf8_fma(acc, a1, __int_as_float(p1.y));
        bf8_fma(acc, a2, __int_as_float(p2.y));
        bf8_fma(acc, a3, __int_as_float(p3.y));
    }
    for (; j < e; ++j) {
        int2 p0 = ev[j];
        uint4 a0 = xb[(size_t)p0.x * 8 + g];
        bf8_fma(acc, a0, __int_as_float(p0.y));
    }
    xn[(size_t)vrow * 8 + g] = pack8(acc);
}

// g1 final: res = alpha*(x0+x1+x2+A*x2); writes bf16 item rows DIRECTLY into
// g2's sorted x0 table at inline-computed sort positions.
__device__ void rol_final1(int bid, const int2* __restrict__ rrp, const int* __restrict__ perm,
                           const int2* __restrict__ ev, const uint4* __restrict__ x2b,
                           const uint4* __restrict__ x1b, const uint4* __restrict__ x0b,
                           const int2* __restrict__ rr2, const int* __restrict__ brk2,
                           const int* __restrict__ ghist2, uint4* __restrict__ xb0s,
                           float alpha, int N) {
    __shared__ int sboff[64];
    scan_boff(ghist2, sboff);
    __syncthreads();
    int idx = bid * B + threadIdx.x;
    int vrow = idx >> 3;
    if (vrow >= N) return;
    int g = idx & 7;
    int2 se = rrp[vrow];
    int row = perm[vrow];
    float acc[8] = {0.f, 0.f, 0.f, 0.f, 0.f, 0.f, 0.f, 0.f};
    int j = se.x, e = se.y;
    for (; j + 3 < e; j += 4) {
        int2 p0 = ev[j], p1 = ev[j + 1], p2 = ev[j + 2], p3 = ev[j + 3];
        uint4 a0 = x2b[(size_t)p0.x * 8 + g];
        uint4 a1 = x2b[(size_t)p1.x * 8 + g];
        uint4 a2 = x2b[(size_t)p2.x * 8 + g];
        uint4 a3 = x2b[(size_t)p3.x * 8 + g];
        bf8_fma(acc, a0, __int_as_float(p0.y));
        bf8_fma(acc, a1, __int_as_float(p1.y));
        bf8_fma(acc, a2, __int_as_float(p2.y));
        bf8_fma(acc, a3, __int_as_float(p3.y));
    }
    for (; j < e; ++j) {
        int2 p0 = ev[j];
        uint4 a0 = x2b[(size_t)p0.x * 8 + g];
        bf8_fma(acc, a0, __int_as_float(p0.y));
    }
    bf8_add(acc, x1b[(size_t)row * 8 + g]);
    bf8_add(acc, x2b[(size_t)row * 8 + g]);
    bf8_add(acc, x0b[(size_t)row * 8 + g]);
    float r[8];
#pragma unroll
    for (int k = 0; k < 8; ++k) r[k] = alpha * acc[k];
    int oi = N_USERS + row;                       // orig id in g2 space
    int2 s2 = rr2[oi];
    int pos = sboff[bin_of(s2.y - s2.x)] + brk2[oi];
    xb0s[(size_t)pos * 8 + g] = pack8(r);
}

// g2 final (sorted space): linear x0s/x1s/x2s adds; out[perm[vrow]] fp32 scatter
__device__ void rol_final_s(int bid, const int2* __restrict__ srr, const int* __restrict__ perm,
                            const int2* __restrict__ ev, const uint4* __restrict__ x2s,
                            const uint4* __restrict__ x1s, const uint4* __restrict__ x0s,
                            float4* __restrict__ out, float alpha, int N) {
    int idx = bid * B + threadIdx.x;
    int vrow = idx >> 3;
    if (vrow >= N) return;
    int g = idx & 7;
    int2 se = srr[vrow];
    float acc[8] = {0.f, 0.f, 0.f, 0.f, 0.f, 0.f, 0.f, 0.f};
    int j = se.x, e = se.y;
    for (; j + 3 < e; j += 4) {
        int2 p0 = ev[j], p1 = ev[j + 1], p2 = ev[j + 2], p3 = ev[j + 3];
        uint4 a0 = x2s[(size_t)p0.x * 8 + g];
        uint4 a1 = x2s[(size_t)p1.x * 8 + g];
        uint4 a2 = x2s[(size_t)p2.x * 8 + g];
        uint4 a3 = x2s[(size_t)p3.x * 8 + g];
        bf8_fma(acc, a0, __int_as_float(p0.y));
        bf8_fma(acc, a1, __int_as_float(p1.y));
        bf8_fma(acc, a2, __int_as_float(p2.y));
        bf8_fma(acc, a3, __int_as_float(p3.y));
    }
    for (; j < e; ++j) {
        int2 p0 = ev[j];
        uint4 a0 = x2s[(size_t)p0.x * 8 + g];
        bf8_fma(acc, a0, __int_as_float(p0.y));
    }
    bf8_add(acc, x1s[(size_t)vrow * 8 + g]);
    bf8_add(acc, x2s[(size_t)vrow * 8 + g]);
    bf8_add(acc, x0s[(size_t)vrow * 8 + g]);
    float r[8];
#pragma unroll
    for (int k = 0; k < 8; ++k) r[k] = alpha * acc[k];
    int orig = perm[vrow];
    out[(size_t)orig * 16 + 2 * g]     = make_float4(r[0], r[1], r[2], r[3]);
    out[(size_t)orig * 16 + 2 * g + 1] = make_float4(r[4], r[5], r[6], r[7]);
}

// ================= fused dispatch kernels (blockIdx range -> role) =================

__global__ void f_cnt_cvt(int nbA, const int* dstA, int* cntA, int* rankA, int eA,
                          const float4* xB, uint4* xbB, int n8B) {
    int b = (int)blockIdx.x;
    if (b < nbA) rol_cnt(b, dstA, cntA, rankA, 0, eA);
    else         rol_cvt(b - nbA, xB, xbB, n8B);
}

__global__ void f_node_cnt(int nbA, const int* cntN, int2* rr, int* brk, int* ghist,
                           int* gcur, int N,
                           const int* dstS, int* cntS, int* rankS, int e0, int e1) {
    int b = (int)blockIdx.x;
    if (b < nbA) rol_node(b, cntN, rr, brk, ghist, gcur, N);
    else         rol_cnt(b - nbA, dstS, cntS, rankS, e0, e1);
}

__global__ void f_fillE_cnt(int nbA, const int* src, const int* dst, const float* w,
                            const int* rank, const int2* rr, int2* ev, int E,
                            const int* dstS, int* cntS, int* rankS, int e0, int e1) {
    int b = (int)blockIdx.x;
    if (b < nbA) rol_fillE(b, src, dst, w, rank, rr, ev, E);
    else         rol_cnt(b - nbA, dstS, cntS, rankS, e0, e1);
}

__global__ void f_deg_cnt(int nbA, const int2* rr, const int2* ev, float* dis, int N,
                          const int* dstS, int* cntS, int* rankS, int e0, int e1) {
    int b = (int)blockIdx.x;
    if (b < nbA) rol_deg(b, rr, ev, dis, N);
    else         rol_cnt(b - nbA, dstS, cntS, rankS, e0, e1);
}

__global__ void f_valsc_cnt(int nbA, const int2* rr, const float* dis, const int* brk,
                            const int* ghist, int2* ev, int* perm, int2* rrp, int N,
                            const int* dstS, int* cntS, int* rankS, int e0, int e1) {
    int b = (int)blockIdx.x;
    if (b < nbA) rol_valsc(b, rr, dis, brk, ghist, ev, perm, rrp, N);
    else         rol_cnt(b - nbA, dstS, cntS, rankS, e0, e1);
}

__global__ void f_spmm_cnt(int nbA, const int2* rrp, const int* perm, const int2* ev,
                           const uint4* xb, uint4* xn, int NA,
                           const int* dstS, int* cntS, int* rankS, int e0, int e1) {
    int b = (int)blockIdx.x;
    if (b < nbA) rol_spmm(b, rrp, perm, ev, xb, xn, NA);
    else         rol_cnt(b - nbA, dstS, cntS, rankS, e0, e1);
}

__global__ void f_spmm_node(int nbA, const int2* rrp, const int* perm, const int2* ev,
                            const uint4* xb, uint4* xn, int NA,
                            const int* cntN, int2* rrB, int* brkB, int* ghistB,
                            int* gcurB, int NB) {
    int b = (int)blockIdx.x;
    if (b < nbA) rol_spmm(b, rrp, perm, ev, xb, xn, NA);
    else         rol_node(b - nbA, cntN, rrB, brkB, ghistB, gcurB, NB);
}

// F8: [final1 | cvt2u_sorted | deg2 | sortfin2]
__global__ void f_final_mix(int nbA, const int2* rrp1, const int* perm1, const int2* ev1,
                            const uint4* x2b, const uint4* x1b, const uint4* x0b,
                            float alpha, int N1,
                            int nbB, const float4* xu,
                            int nbC, const int2* rr2, const int2* ev2, float* dis2, int N2,
                            const int* brk2, const int* ghist2, uint4* xb0s,
                            int* sortpos2, int* perm2, int2* srr2) {
    int b = (int)blockIdx.x;
    if (b < nbA) { rol_final1(b, rrp1, perm1, ev1, x2b, x1b, x0b,
                              rr2, brk2, ghist2, xb0s, alpha, N1); return; }
    b -= nbA;
    if (b < nbB) { rol_cvts(b, xu, rr2, brk2, ghist2, xb0s, N_USERS); return; }
    b -= nbB;
    if (b < nbC) { rol_deg(b, rr2, ev2, dis2, N2); return; }
    rol_sortfin(b - nbC, rr2, brk2, ghist2, sortpos2, perm2, srr2, N2);
}

// plain single-role kernels
__global__ void k_fill(const int* src, const int* dst, const float* w, const int* rank,
                       const int2* rr, int2* ev, int E) {
    rol_fillE((int)blockIdx.x, src, dst, w, rank, rr, ev, E);
}
__global__ void k_evnorm(const int2* rr, const float* dis, const int* sortpos,
                         int2* ev, int N) {
    rol_evnorm((int)blockIdx.x, rr, dis, sortpos, ev, N);
}
__global__ void k_spmm_s(const int2* srr, const int2* ev, const uint4* xb,
                         uint4* xn, int N) {
    rol_spmm_s((int)blockIdx.x, srr, ev, xb, xn, N);
}
__global__ void k_final_s(const int2* srr, const int* perm, const int2* ev,
                          const uint4* x2s, const uint4* x1s, const uint4* x0s,
                          float4* out, float alpha, int N) {
    rol_final_s((int)blockIdx.x, srr, perm, ev, x2s, x1s, x0s, out, alpha, N);
}

// ================= host-side orchestration =================

static inline int nbx(long long work, int per) { return (int)((work + per - 1) / per); }

extern "C" void kernel_launch(void* const* d_in, const int* in_sizes, int n_in,
                              void* d_out, int out_size, void* d_ws, size_t ws_size,
                              hipStream_t stream) {
    const float* emb_ii  = (const float*)d_in[0];
    const float* emb_uiu = (const float*)d_in[1];
    const float* w_ii    = (const float*)d_in[2];
    const float* w_uiu   = (const float*)d_in[3];
    const int*   src_ii  = (const int*)d_in[4];
    const int*   dst_ii  = src_ii + E_II;
    const int*   src_uiu = (const int*)d_in[5];
    const int*   dst_uiu = src_uiu + E_UIU;
    float*       out     = (float*)d_out;

    // ---- workspace (95.2 MB, layout identical to R10) ----
    uint4* xb0_u = (uint4*)d_ws;
    uint4* x1_u  = xb0_u + (size_t)N_UIU * 8;
    uint4* x2_u  = x1_u + (size_t)N_UIU * 8;

    // g1 build block in x2_u second half (dead after F8; z2 written F11)
    int2*  ev1   = (int2*)(x2_u + (size_t)N_II * 8);
    int*   rank1 = (int*)(ev1 + E_II);
    int2*  rr1   = (int2*)(rank1 + E_II);
    int*   cnt1  = (int*)(rr1 + N_II);
    int*   gt1   = cnt1 + N_II;                 // gcur | ghist[64]
    float* dis1  = (float*)(gt1 + 65);
    int*   brk1  = (int*)(dis1 + N_II);
    int*   perm1 = rank1;                       // alias post-fillE1
    int2*  rrp1  = (int2*)(rank1 + N_II);

    // g2 build block (tail)
    int2*  ev2   = (int2*)(x2_u + (size_t)N_UIU * 8);
    int*   rank2 = (int*)(ev2 + E_UIU);
    int*   perm2 = rank2;                       // alias: written F8 (rank2 dead after F7)
    int2*  srr2  = (int2*)(rank2 + N_UIU);      // alias, same region
    int2*  rr2   = (int2*)(rank2 + E_UIU);
    int*   cnt2  = (int*)(rr2 + N_UIU);
    int*   sortpos2 = cnt2;                     // alias: written F8 (cnt2 dead after F6)
    int*   gt2   = cnt2 + N_UIU;                // gcur | ghist[64]
    int*   brk2  = gt2 + 65;
    float* dis2  = (float*)(brk2 + N_UIU);

    uint4* g1_x0 = x1_u;                         // 12.8MB
    uint4* g1_x1 = x1_u + (size_t)N_II * 8;      // 12.8MB
    uint4* g1_x2 = x2_u;                         // 12.8MB (x2_u 1st half)

    const float alpha = 0.25f;    // 1/(L+1), L=3 both graphs

    hipMemsetAsync(cnt1, 0, ((size_t)N_II + 65) * sizeof(int), stream);
    hipMemsetAsync(cnt2, 0, ((size_t)N_UIU + 65) * sizeof(int), stream);

    // cnt2 slices: 5 x 240K edges across F1-F5 (atomic floor ~11us each,
    // hidden under g1's node/fillE/deg/valsc/spmm1)
    const int s[6] = {0, 240000, 480000, 720000, 960000, E_UIU};

    const int nbCnt1 = nbx(E_II, B * CR_K);
    const int nbCvt1 = nbx((long long)N_II * 8, B);
    const int nbN1   = nbx(N_II, B);
    const int nbF1   = nbx(E_II, B * FE_K);
    const int nbS1   = nbx((long long)N_II * 8, B);
    const int nbN2   = nbx(N_UIU, B);
    const int nbF2   = nbx(E_UIU, B * FE_K);
    const int nbS2   = nbx((long long)N_UIU * 8, B);
    const int nbCvt2 = nbx((long long)N_USERS * 8, B);

    // F0: g1 count | g1 x0 bf16 conversion
    f_cnt_cvt<<<nbCnt1 + nbCvt1, B, 0, stream>>>(
        nbCnt1, dst_ii, cnt1, rank1, E_II,
        (const float4*)emb_ii, g1_x0, N_II * 8);

    // F1: g1 node | cnt2 slice 0
    f_node_cnt<<<nbN1 + nbx(s[1] - s[0], B * CR_K), B, 0, stream>>>(
        nbN1, cnt1, rr1, brk1, gt1 + 1, gt1, N_II,
        dst_uiu, cnt2, rank2, s[0], s[1]);

    // F2: g1 fillE | cnt2 slice 1
    f_fillE_cnt<<<nbF1 + nbx(s[2] - s[1], B * CR_K), B, 0, stream>>>(
        nbF1, src_ii, dst_ii, w_ii, rank1, rr1, ev1, E_II,
        dst_uiu, cnt2, rank2, s[1], s[2]);

    // F3: g1 deg | cnt2 slice 2
    f_deg_cnt<<<nbN1 + nbx(s[3] - s[2], B * CR_K), B, 0, stream>>>(
        nbN1, rr1, ev1, dis1, N_II,
        dst_uiu, cnt2, rank2, s[2], s[3]);

    // F4: g1 val+scatter | cnt2 slice 3
    f_valsc_cnt<<<nbN1 + nbx(s[4] - s[3], B * CR_K), B, 0, stream>>>(
        nbN1, rr1, dis1, brk1, gt1 + 1, ev1, perm1, rrp1, N_II,
        dst_uiu, cnt2, rank2, s[3], s[4]);

    // F5: g1 spmm layer1 | cnt2 slice 4 (cnt2 complete)
    f_spmm_cnt<<<nbS1 + nbx(s[5] - s[4], B * CR_K), B, 0, stream>>>(
        nbS1, rrp1, perm1, ev1, g1_x0, g1_x1, N_II,
        dst_uiu, cnt2, rank2, s[4], s[5]);

    // F6: g1 spmm layer2 | g2 node
    f_spmm_node<<<nbS1 + nbN2, B, 0, stream>>>(
        nbS1, rrp1, perm1, ev1, g1_x1, g1_x2, N_II,
        cnt2, rr2, brk2, gt2 + 1, gt2, N_UIU);

    // F7: g2 fillE ALONE (scatter-store role; no cache-sensitive co-tenant)
    k_fill<<<nbF2, B, 0, stream>>>(src_uiu, dst_uiu, w_uiu, rank2, rr2, ev2, E_UIU);

    // F8: g1 final (-> sorted g2 x0) | cvt2u sorted | g2 deg | g2 sortfin
    f_final_mix<<<nbS1 + nbCvt2 + nbN2 + nbN2, B, 0, stream>>>(
        nbS1, rrp1, perm1, ev1, g1_x2, g1_x1, g1_x0, alpha, N_II,
        nbCvt2, (const float4*)emb_uiu,
        nbN2, rr2, ev2, dis2, N_UIU,
        brk2, gt2 + 1, xb0_u, sortpos2, perm2, srr2);

    // F9: g2 evnorm (normalize + remap ev.x -> sorted)
    k_evnorm<<<nbN2, B, 0, stream>>>(rr2, dis2, sortpos2, ev2, N_UIU);

    // F10-F12: g2 spmm chain in sorted space
    k_spmm_s<<<nbS2, B, 0, stream>>>(srr2, ev2, xb0_u, x1_u, N_UIU);
    k_spmm_s<<<nbS2, B, 0, stream>>>(srr2, ev2, x1_u, x2_u, N_UIU);
    k_final_s<<<nbS2, B, 0, stream>>>(srr2, perm2, ev2, x2_u, x1_u, xb0_u,
                                      (float4*)out, alpha, N_UIU);
}